// Round 1
// baseline (2769.208 us; speedup 1.0000x reference)
//
#include <hip/hip_runtime.h>
#include <hip/hip_bf16.h>

typedef __bf16 bf16x8 __attribute__((ext_vector_type(8)));
typedef float  f32x4  __attribute__((ext_vector_type(4)));
typedef unsigned short u16;

#define GLDS16(gsrc, ldst)                                                        \
  __builtin_amdgcn_global_load_lds(                                               \
      (const __attribute__((address_space(1))) unsigned int*)(gsrc),              \
      (__attribute__((address_space(3))) unsigned int*)(ldst), 16, 0, 0)

__device__ __forceinline__ u16 f2b(float f) {
  unsigned int u = __builtin_bit_cast(unsigned int, f);
  u = (u + 0x7fffu + ((u >> 16) & 1u)) >> 16;
  return (u16)u;
}
__device__ __forceinline__ float b2f(u16 b) {
  unsigned int u = ((unsigned int)b) << 16;
  return __builtin_bit_cast(float, u);
}

// ---------------- fp32 -> bf16 convert (vectorized, grid-stride) ----------------
__global__ __launch_bounds__(256) void cvt_kernel(const float4* __restrict__ in,
                                                  ushort4* __restrict__ out, int n4) {
  int i = blockIdx.x * blockDim.x + threadIdx.x;
  int stride = gridDim.x * blockDim.x;
  for (; i < n4; i += stride) {
    float4 v = in[i];
    ushort4 o;
    o.x = f2b(v.x); o.y = f2b(v.y); o.z = f2b(v.z); o.w = f2b(v.w);
    out[i] = o;
  }
}

// ---------------- LoRA rank-projection: t[m][r] = sum_k Xb[m][k] * A[r][k] ------
// Xb bf16 [2048][K]; A fp32 [L][R][16][K]; t fp32 [2048][16]
// grid = 32 blocks x 256 thr; each wave does 16 rows, full K.
__global__ __launch_bounds__(256) void lora_t_kernel(const u16* __restrict__ Xb, int K,
                                                     const float* __restrict__ A1,
                                                     const float* __restrict__ A2,
                                                     const int* __restrict__ lidx,
                                                     const int* __restrict__ layer,
                                                     float* __restrict__ t1,
                                                     float* __restrict__ t2) {
  const int lane = threadIdx.x & 63, wid = threadIdx.x >> 6;
  const int m0 = blockIdx.x * 64 + wid * 16;
  const int li = lidx[m0 >> 9];
  const size_t abase = ((size_t)layer[0] * 16 + li) * 16 * (size_t)K;
  const int r = lane & 15, kg = lane >> 4;
  f32x4 acc1 = {0.f, 0.f, 0.f, 0.f}, acc2 = {0.f, 0.f, 0.f, 0.f};
  for (int k0 = 0; k0 < K; k0 += 32) {
    bf16x8 a = *(const bf16x8*)&Xb[(size_t)(m0 + r) * K + k0 + kg * 8];
    const float* ap = A1 + abase + (size_t)r * K + k0 + kg * 8;
    float4 f0 = *(const float4*)ap;
    float4 f1 = *(const float4*)(ap + 4);
    bf16x8 b;
    b[0] = (__bf16)f0.x; b[1] = (__bf16)f0.y; b[2] = (__bf16)f0.z; b[3] = (__bf16)f0.w;
    b[4] = (__bf16)f1.x; b[5] = (__bf16)f1.y; b[6] = (__bf16)f1.z; b[7] = (__bf16)f1.w;
    acc1 = __builtin_amdgcn_mfma_f32_16x16x32_bf16(a, b, acc1, 0, 0, 0);
    if (A2) {
      const float* ap2 = A2 + abase + (size_t)r * K + k0 + kg * 8;
      float4 g0 = *(const float4*)ap2;
      float4 g1 = *(const float4*)(ap2 + 4);
      bf16x8 b2;
      b2[0] = (__bf16)g0.x; b2[1] = (__bf16)g0.y; b2[2] = (__bf16)g0.z; b2[3] = (__bf16)g0.w;
      b2[4] = (__bf16)g1.x; b2[5] = (__bf16)g1.y; b2[6] = (__bf16)g1.z; b2[7] = (__bf16)g1.w;
      acc2 = __builtin_amdgcn_mfma_f32_16x16x32_bf16(a, b2, acc2, 0, 0, 0);
    }
  }
#pragma unroll
  for (int j = 0; j < 4; ++j) {
    int m = m0 + (lane >> 4) * 4 + j;
    t1[(size_t)m * 16 + (lane & 15)] = acc1[j];
    if (A2) t2[(size_t)m * 16 + (lane & 15)] = acc2[j];
  }
}

// ---------------- fused gate+up GEMM + LoRA + SwiGLU -> act bf16 ----------------
// C_g = Xb @ Wg^T, C_u = Xb @ Wu^T ; act = silu(g + 0.5*t_g Bg^T) * (u + 0.5*t_u Bu^T)
// tile 128x128, BK=64, 256 thr (4 waves 2x2, each 64x64 = 4x4 frags of 16x16)
__global__ __launch_bounds__(256) void gemm_gateup(
    const u16* __restrict__ Xb, const u16* __restrict__ Wg, const u16* __restrict__ Wu,
    const float* __restrict__ tg, const float* __restrict__ tu,
    const float* __restrict__ Bg, const float* __restrict__ Bu,
    const int* __restrict__ lidx, const int* __restrict__ layer,
    u16* __restrict__ act) {
  constexpr int K = 4096, F = 11008;
  __shared__ alignas(16) u16 lA[128 * 64];
  __shared__ alignas(16) u16 lG[128 * 64];
  __shared__ alignas(16) u16 lU[128 * 64];
  const int tid = threadIdx.x, lane = tid & 63, wid = tid >> 6;
  const int wr = wid >> 1, wc = wid & 1;
  const int m0 = blockIdx.x * 128, n0 = blockIdx.y * 128;

  f32x4 accG[4][4] = {}, accU[4][4] = {};

  for (int k0 = 0; k0 < K; k0 += 64) {
#pragma unroll
    for (int i = 0; i < 4; ++i) {
      int e = wid * 2048 + i * 512 + lane * 8;
      int row = e >> 6, col = e & 63;
      int ldso = wid * 2048 + i * 512;
      GLDS16(Xb + (size_t)(m0 + row) * K + k0 + col, &lA[ldso]);
      GLDS16(Wg + (size_t)(n0 + row) * K + k0 + col, &lG[ldso]);
      GLDS16(Wu + (size_t)(n0 + row) * K + k0 + col, &lU[ldso]);
    }
    __syncthreads();
#pragma unroll
    for (int kk = 0; kk < 2; ++kk) {
      bf16x8 a[4], bg[4], bu[4];
#pragma unroll
      for (int mi = 0; mi < 4; ++mi)
        a[mi] = *(const bf16x8*)&lA[(wr * 64 + mi * 16 + (lane & 15)) * 64 + kk * 32 + (lane >> 4) * 8];
#pragma unroll
      for (int ni = 0; ni < 4; ++ni) {
        int off = (wc * 64 + ni * 16 + (lane & 15)) * 64 + kk * 32 + (lane >> 4) * 8;
        bg[ni] = *(const bf16x8*)&lG[off];
        bu[ni] = *(const bf16x8*)&lU[off];
      }
#pragma unroll
      for (int mi = 0; mi < 4; ++mi)
#pragma unroll
        for (int ni = 0; ni < 4; ++ni) {
          accG[mi][ni] = __builtin_amdgcn_mfma_f32_16x16x32_bf16(a[mi], bg[ni], accG[mi][ni], 0, 0, 0);
          accU[mi][ni] = __builtin_amdgcn_mfma_f32_16x16x32_bf16(a[mi], bu[ni], accU[mi][ni], 0, 0, 0);
        }
    }
    __syncthreads();
  }

  // ---- epilogue: LoRA + SwiGLU ----
  float* ltg = (float*)lA;  // 2048 floats
  float* ltu = (float*)lG;
  for (int i = tid; i < 2048; i += 256) {
    ltg[i] = tg[(size_t)m0 * 16 + i];
    ltu[i] = tu[(size_t)m0 * 16 + i];
  }
  __syncthreads();
  const int li = lidx[m0 >> 9];
  const size_t bbase = ((size_t)layer[0] * 16 + li) * (size_t)F * 16;
#pragma unroll
  for (int ni = 0; ni < 4; ++ni) {
    int c = wc * 64 + ni * 16 + (lane & 15);  // local col
    const float* bgp = Bg + bbase + (size_t)(n0 + c) * 16;
    const float* bup = Bu + bbase + (size_t)(n0 + c) * 16;
    float bgv[16], buv[16];
#pragma unroll
    for (int q = 0; q < 4; ++q) {
      *(float4*)&bgv[q * 4] = *(const float4*)&bgp[q * 4];
      *(float4*)&buv[q * 4] = *(const float4*)&bup[q * 4];
    }
#pragma unroll
    for (int mi = 0; mi < 4; ++mi) {
#pragma unroll
      for (int j = 0; j < 4; ++j) {
        int r_ = wr * 64 + mi * 16 + (lane >> 4) * 4 + j;  // local row
        float g = accG[mi][ni][j], u = accU[mi][ni][j];
        float lg = 0.f, lu = 0.f;
#pragma unroll
        for (int r = 0; r < 16; ++r) {
          lg += ltg[r_ * 16 + r] * bgv[r];
          lu += ltu[r_ * 16 + r] * buv[r];
        }
        g += 0.5f * lg;
        u += 0.5f * lu;
        float s = g / (1.f + __expf(-g));
        act[(size_t)(m0 + r_) * F + (n0 + c)] = f2b(s * u);
      }
    }
  }
}

// ---------------- down GEMM + LoRA -> out fp32 ----------------
__global__ __launch_bounds__(256) void gemm_down(
    const u16* __restrict__ Ab, const u16* __restrict__ Wd,
    const float* __restrict__ td, const float* __restrict__ Bd,
    const int* __restrict__ lidx, const int* __restrict__ layer,
    float* __restrict__ out) {
  constexpr int K = 11008, H = 4096;
  __shared__ alignas(16) u16 lA[128 * 64];
  __shared__ alignas(16) u16 lB[128 * 64];
  const int tid = threadIdx.x, lane = tid & 63, wid = tid >> 6;
  const int wr = wid >> 1, wc = wid & 1;
  const int m0 = blockIdx.x * 128, n0 = blockIdx.y * 128;

  f32x4 acc[4][4] = {};

  for (int k0 = 0; k0 < K; k0 += 64) {
#pragma unroll
    for (int i = 0; i < 4; ++i) {
      int e = wid * 2048 + i * 512 + lane * 8;
      int row = e >> 6, col = e & 63;
      int ldso = wid * 2048 + i * 512;
      GLDS16(Ab + (size_t)(m0 + row) * K + k0 + col, &lA[ldso]);
      GLDS16(Wd + (size_t)(n0 + row) * K + k0 + col, &lB[ldso]);
    }
    __syncthreads();
#pragma unroll
    for (int kk = 0; kk < 2; ++kk) {
      bf16x8 a[4], b[4];
#pragma unroll
      for (int mi = 0; mi < 4; ++mi)
        a[mi] = *(const bf16x8*)&lA[(wr * 64 + mi * 16 + (lane & 15)) * 64 + kk * 32 + (lane >> 4) * 8];
#pragma unroll
      for (int ni = 0; ni < 4; ++ni)
        b[ni] = *(const bf16x8*)&lB[(wc * 64 + ni * 16 + (lane & 15)) * 64 + kk * 32 + (lane >> 4) * 8];
#pragma unroll
      for (int mi = 0; mi < 4; ++mi)
#pragma unroll
        for (int ni = 0; ni < 4; ++ni)
          acc[mi][ni] = __builtin_amdgcn_mfma_f32_16x16x32_bf16(a[mi], b[ni], acc[mi][ni], 0, 0, 0);
    }
    __syncthreads();
  }

  float* ltd = (float*)lA;
  for (int i = tid; i < 2048; i += 256) ltd[i] = td[(size_t)m0 * 16 + i];
  __syncthreads();
  const int li = lidx[m0 >> 9];
  const size_t bbase = ((size_t)layer[0] * 16 + li) * (size_t)H * 16;
#pragma unroll
  for (int ni = 0; ni < 4; ++ni) {
    int c = wc * 64 + ni * 16 + (lane & 15);
    const float* bp = Bd + bbase + (size_t)(n0 + c) * 16;
    float bv[16];
#pragma unroll
    for (int q = 0; q < 4; ++q) *(float4*)&bv[q * 4] = *(const float4*)&bp[q * 4];
#pragma unroll
    for (int mi = 0; mi < 4; ++mi) {
#pragma unroll
      for (int j = 0; j < 4; ++j) {
        int r_ = wr * 64 + mi * 16 + (lane >> 4) * 4 + j;
        float lsum = 0.f;
#pragma unroll
        for (int r = 0; r < 16; ++r) lsum += ltd[r_ * 16 + r] * bv[r];
        out[(size_t)(m0 + r_) * H + (n0 + c)] = acc[mi][ni][j] + 0.5f * lsum;
      }
    }
  }
}

extern "C" void kernel_launch(void* const* d_in, const int* in_sizes, int n_in,
                              void* d_out, int out_size, void* d_ws, size_t ws_size,
                              hipStream_t stream) {
  const float* x  = (const float*)d_in[0];
  const float* Wg = (const float*)d_in[1];
  const float* Wu = (const float*)d_in[2];
  const float* Wd = (const float*)d_in[3];
  const float* Ag = (const float*)d_in[4];
  const float* Bg = (const float*)d_in[5];
  const float* Au = (const float*)d_in[6];
  const float* Bu = (const float*)d_in[7];
  const float* Ad = (const float*)d_in[8];
  const float* Bd = (const float*)d_in[9];
  const int* lidx = (const int*)d_in[10];
  const int* lay  = (const int*)d_in[11];
  float* out = (float*)d_out;

  // ws layout (bytes)
  char* ws = (char*)d_ws;
  u16*  xb   = (u16*)(ws + 0);            //  16,777,216  x bf16 [2048][4096]
  u16*  wgb  = (u16*)(ws + 16777216);     //  90,177,536  Wg bf16 [11008][4096]
  u16*  wub  = (u16*)(ws + 106954752);    //  90,177,536  Wu bf16
  u16*  wdb  = (u16*)(ws + 197132288);    //  90,177,536  Wd bf16 [4096][11008]
  u16*  actb = (u16*)(ws + 287309824);    //  45,088,768  act bf16 [2048][11008]
  float* tg  = (float*)(ws + 332398592);  //  131,072
  float* tu  = (float*)(ws + 332529664);  //  131,072
  float* td  = (float*)(ws + 332660736);  //  131,072

  cvt_kernel<<<1024, 256, 0, stream>>>((const float4*)x,  (ushort4*)xb,  8388608 / 4);
  cvt_kernel<<<2048, 256, 0, stream>>>((const float4*)Wg, (ushort4*)wgb, 45088768 / 4);
  cvt_kernel<<<2048, 256, 0, stream>>>((const float4*)Wu, (ushort4*)wub, 45088768 / 4);
  cvt_kernel<<<2048, 256, 0, stream>>>((const float4*)Wd, (ushort4*)wdb, 45088768 / 4);

  lora_t_kernel<<<32, 256, 0, stream>>>(xb, 4096, Ag, Au, lidx, lay, tg, tu);

  gemm_gateup<<<dim3(16, 86), 256, 0, stream>>>(xb, wgb, wub, tg, tu, Bg, Bu, lidx, lay, actb);

  lora_t_kernel<<<32, 256, 0, stream>>>(actb, 11008, Ad, nullptr, lidx, lay, td, nullptr);

  gemm_down<<<dim3(16, 32), 256, 0, stream>>>(actb, wdb, td, Bd, lidx, lay, out);
}

// Round 2
// 2380.099 us; speedup vs baseline: 1.1635x; 1.1635x over previous
//
#include <hip/hip_runtime.h>
#include <hip/hip_bf16.h>

typedef __bf16 bf16x8 __attribute__((ext_vector_type(8)));
typedef float  f32x4  __attribute__((ext_vector_type(4)));
typedef unsigned short u16;

#define GLDS16(gsrc, ldst)                                                        \
  __builtin_amdgcn_global_load_lds(                                               \
      (const __attribute__((address_space(1))) unsigned int*)(gsrc),              \
      (__attribute__((address_space(3))) unsigned int*)(ldst), 16, 0, 0)

__device__ __forceinline__ u16 f2b(float f) {
  unsigned int u = __builtin_bit_cast(unsigned int, f);
  u = (u + 0x7fffu + ((u >> 16) & 1u)) >> 16;
  return (u16)u;
}
__device__ __forceinline__ float b2f(u16 b) {
  unsigned int u = ((unsigned int)b) << 16;
  return __builtin_bit_cast(float, u);
}

// ---------------- fp32 -> bf16 convert (vectorized, grid-stride) ----------------
__global__ __launch_bounds__(256) void cvt_kernel(const float4* __restrict__ in,
                                                  ushort4* __restrict__ out, int n4) {
  int i = blockIdx.x * blockDim.x + threadIdx.x;
  int stride = gridDim.x * blockDim.x;
  for (; i < n4; i += stride) {
    float4 v = in[i];
    ushort4 o;
    o.x = f2b(v.x); o.y = f2b(v.y); o.z = f2b(v.z); o.w = f2b(v.w);
    out[i] = o;
  }
}

// ---------------- LoRA rank-projection: t[m][r] = sum_k Xb[m][k] * A[r][k] ------
__global__ __launch_bounds__(256) void lora_t_kernel(const u16* __restrict__ Xb, int K,
                                                     const float* __restrict__ A1,
                                                     const float* __restrict__ A2,
                                                     const int* __restrict__ lidx,
                                                     const int* __restrict__ layer,
                                                     float* __restrict__ t1,
                                                     float* __restrict__ t2) {
  const int lane = threadIdx.x & 63, wid = threadIdx.x >> 6;
  const int m0 = blockIdx.x * 64 + wid * 16;
  const int li = lidx[m0 >> 9];
  const size_t abase = ((size_t)layer[0] * 16 + li) * 16 * (size_t)K;
  const int r = lane & 15, kg = lane >> 4;
  f32x4 acc1 = {0.f, 0.f, 0.f, 0.f}, acc2 = {0.f, 0.f, 0.f, 0.f};
  for (int k0 = 0; k0 < K; k0 += 32) {
    bf16x8 a = *(const bf16x8*)&Xb[(size_t)(m0 + r) * K + k0 + kg * 8];
    const float* ap = A1 + abase + (size_t)r * K + k0 + kg * 8;
    float4 f0 = *(const float4*)ap;
    float4 f1 = *(const float4*)(ap + 4);
    bf16x8 b;
    b[0] = (__bf16)f0.x; b[1] = (__bf16)f0.y; b[2] = (__bf16)f0.z; b[3] = (__bf16)f0.w;
    b[4] = (__bf16)f1.x; b[5] = (__bf16)f1.y; b[6] = (__bf16)f1.z; b[7] = (__bf16)f1.w;
    acc1 = __builtin_amdgcn_mfma_f32_16x16x32_bf16(a, b, acc1, 0, 0, 0);
    if (A2) {
      const float* ap2 = A2 + abase + (size_t)r * K + k0 + kg * 8;
      float4 g0 = *(const float4*)ap2;
      float4 g1 = *(const float4*)(ap2 + 4);
      bf16x8 b2;
      b2[0] = (__bf16)g0.x; b2[1] = (__bf16)g0.y; b2[2] = (__bf16)g0.z; b2[3] = (__bf16)g0.w;
      b2[4] = (__bf16)g1.x; b2[5] = (__bf16)g1.y; b2[6] = (__bf16)g1.z; b2[7] = (__bf16)g1.w;
      acc2 = __builtin_amdgcn_mfma_f32_16x16x32_bf16(a, b2, acc2, 0, 0, 0);
    }
  }
#pragma unroll
  for (int j = 0; j < 4; ++j) {
    int m = m0 + (lane >> 4) * 4 + j;
    t1[(size_t)m * 16 + (lane & 15)] = acc1[j];
    if (A2) t2[(size_t)m * 16 + (lane & 15)] = acc2[j];
  }
}

// ---------------- gate / up GEMM (128x128 tile, BK=64, 4 waves 2x2) -------------
// IS_UP=0: sg[m][n] = silu(Xb.Wg^T + 0.5 * tg.Bg^T)          (write bf16)
// IS_UP=1: act[m][n] = sg[m][n] * (Xb.Wu^T + 0.5 * tu.Bu^T)  (in-place over sg)
template <int IS_UP>
__global__ __launch_bounds__(256) void gemm_gu(
    const u16* __restrict__ Xb, const u16* __restrict__ W,
    const float* __restrict__ t, const float* __restrict__ Bw,
    const int* __restrict__ lidx, const int* __restrict__ layer,
    u16* __restrict__ io) {
  constexpr int K = 4096, F = 11008;
  __shared__ alignas(16) u16 lA[128 * 64];
  __shared__ alignas(16) u16 lB[128 * 64];
  const int tid = threadIdx.x, lane = tid & 63, wid = tid >> 6;
  const int wr = wid >> 1, wc = wid & 1;
  const int m0 = blockIdx.x * 128, n0 = blockIdx.y * 128;

  f32x4 acc[4][4] = {};

  for (int k0 = 0; k0 < K; k0 += 64) {
#pragma unroll
    for (int i = 0; i < 4; ++i) {
      int e = wid * 2048 + i * 512 + lane * 8;
      int row = e >> 6, col = e & 63;
      int ldso = wid * 2048 + i * 512;
      GLDS16(Xb + (size_t)(m0 + row) * K + k0 + col, &lA[ldso]);
      GLDS16(W + (size_t)(n0 + row) * K + k0 + col, &lB[ldso]);
    }
    __syncthreads();
#pragma unroll
    for (int kk = 0; kk < 2; ++kk) {
      bf16x8 a[4], b[4];
#pragma unroll
      for (int mi = 0; mi < 4; ++mi)
        a[mi] = *(const bf16x8*)&lA[(wr * 64 + mi * 16 + (lane & 15)) * 64 + kk * 32 + (lane >> 4) * 8];
#pragma unroll
      for (int ni = 0; ni < 4; ++ni)
        b[ni] = *(const bf16x8*)&lB[(wc * 64 + ni * 16 + (lane & 15)) * 64 + kk * 32 + (lane >> 4) * 8];
#pragma unroll
      for (int mi = 0; mi < 4; ++mi)
#pragma unroll
        for (int ni = 0; ni < 4; ++ni)
          acc[mi][ni] = __builtin_amdgcn_mfma_f32_16x16x32_bf16(a[mi], b[ni], acc[mi][ni], 0, 0, 0);
    }
    __syncthreads();
  }

  // ---- epilogue: LoRA (+ silu or * gate) ----
  float* lt = (float*)lA;  // 2048 floats of t for this m-tile
  for (int i = tid; i < 2048; i += 256) lt[i] = t[(size_t)m0 * 16 + i];
  __syncthreads();
  const int li = lidx[m0 >> 9];
  const size_t bbase = ((size_t)layer[0] * 16 + li) * (size_t)F * 16;
#pragma unroll
  for (int ni = 0; ni < 4; ++ni) {
    int c = wc * 64 + ni * 16 + (lane & 15);
    const float* bp = Bw + bbase + (size_t)(n0 + c) * 16;
    float bv[16];
#pragma unroll
    for (int q = 0; q < 4; ++q) *(float4*)&bv[q * 4] = *(const float4*)&bp[q * 4];
#pragma unroll
    for (int mi = 0; mi < 4; ++mi) {
#pragma unroll
      for (int j = 0; j < 4; ++j) {
        int r_ = wr * 64 + mi * 16 + (lane >> 4) * 4 + j;
        float v = acc[mi][ni][j];
        float l = 0.f;
#pragma unroll
        for (int r = 0; r < 16; ++r) l += lt[r_ * 16 + r] * bv[r];
        v += 0.5f * l;
        size_t oidx = (size_t)(m0 + r_) * F + (n0 + c);
        if (IS_UP) {
          float g = b2f(io[oidx]);
          io[oidx] = f2b(g * v);
        } else {
          float s = v / (1.f + __expf(-v));
          io[oidx] = f2b(s);
        }
      }
    }
  }
}

// ---------------- down GEMM + LoRA -> out fp32 ----------------
__global__ __launch_bounds__(256) void gemm_down(
    const u16* __restrict__ Ab, const u16* __restrict__ Wd,
    const float* __restrict__ td, const float* __restrict__ Bd,
    const int* __restrict__ lidx, const int* __restrict__ layer,
    float* __restrict__ out) {
  constexpr int K = 11008, H = 4096;
  __shared__ alignas(16) u16 lA[128 * 64];
  __shared__ alignas(16) u16 lB[128 * 64];
  const int tid = threadIdx.x, lane = tid & 63, wid = tid >> 6;
  const int wr = wid >> 1, wc = wid & 1;
  const int m0 = blockIdx.x * 128, n0 = blockIdx.y * 128;

  f32x4 acc[4][4] = {};

  for (int k0 = 0; k0 < K; k0 += 64) {
#pragma unroll
    for (int i = 0; i < 4; ++i) {
      int e = wid * 2048 + i * 512 + lane * 8;
      int row = e >> 6, col = e & 63;
      int ldso = wid * 2048 + i * 512;
      GLDS16(Ab + (size_t)(m0 + row) * K + k0 + col, &lA[ldso]);
      GLDS16(Wd + (size_t)(n0 + row) * K + k0 + col, &lB[ldso]);
    }
    __syncthreads();
#pragma unroll
    for (int kk = 0; kk < 2; ++kk) {
      bf16x8 a[4], b[4];
#pragma unroll
      for (int mi = 0; mi < 4; ++mi)
        a[mi] = *(const bf16x8*)&lA[(wr * 64 + mi * 16 + (lane & 15)) * 64 + kk * 32 + (lane >> 4) * 8];
#pragma unroll
      for (int ni = 0; ni < 4; ++ni)
        b[ni] = *(const bf16x8*)&lB[(wc * 64 + ni * 16 + (lane & 15)) * 64 + kk * 32 + (lane >> 4) * 8];
#pragma unroll
      for (int mi = 0; mi < 4; ++mi)
#pragma unroll
        for (int ni = 0; ni < 4; ++ni)
          acc[mi][ni] = __builtin_amdgcn_mfma_f32_16x16x32_bf16(a[mi], b[ni], acc[mi][ni], 0, 0, 0);
    }
    __syncthreads();
  }

  float* ltd = (float*)lA;
  for (int i = tid; i < 2048; i += 256) ltd[i] = td[(size_t)m0 * 16 + i];
  __syncthreads();
  const int li = lidx[m0 >> 9];
  const size_t bbase = ((size_t)layer[0] * 16 + li) * (size_t)H * 16;
#pragma unroll
  for (int ni = 0; ni < 4; ++ni) {
    int c = wc * 64 + ni * 16 + (lane & 15);
    const float* bp = Bd + bbase + (size_t)(n0 + c) * 16;
    float bv[16];
#pragma unroll
    for (int q = 0; q < 4; ++q) *(float4*)&bv[q * 4] = *(const float4*)&bp[q * 4];
#pragma unroll
    for (int mi = 0; mi < 4; ++mi) {
#pragma unroll
      for (int j = 0; j < 4; ++j) {
        int r_ = wr * 64 + mi * 16 + (lane >> 4) * 4 + j;
        float lsum = 0.f;
#pragma unroll
        for (int r = 0; r < 16; ++r) lsum += ltd[r_ * 16 + r] * bv[r];
        out[(size_t)(m0 + r_) * H + (n0 + c)] = acc[mi][ni][j] + 0.5f * lsum;
      }
    }
  }
}

extern "C" void kernel_launch(void* const* d_in, const int* in_sizes, int n_in,
                              void* d_out, int out_size, void* d_ws, size_t ws_size,
                              hipStream_t stream) {
  const float* x  = (const float*)d_in[0];
  const float* Wg = (const float*)d_in[1];
  const float* Wu = (const float*)d_in[2];
  const float* Wd = (const float*)d_in[3];
  const float* Ag = (const float*)d_in[4];
  const float* Bg = (const float*)d_in[5];
  const float* Au = (const float*)d_in[6];
  const float* Bu = (const float*)d_in[7];
  const float* Ad = (const float*)d_in[8];
  const float* Bd = (const float*)d_in[9];
  const int* lidx = (const int*)d_in[10];
  const int* lay  = (const int*)d_in[11];
  float* out = (float*)d_out;

  // ws layout (bytes)
  char* ws = (char*)d_ws;
  u16*  xb   = (u16*)(ws + 0);            //  16,777,216  x bf16 [2048][4096]
  u16*  wgb  = (u16*)(ws + 16777216);     //  90,177,536  Wg bf16 [11008][4096]
  u16*  wub  = (u16*)(ws + 106954752);    //  90,177,536  Wu bf16
  u16*  wdb  = (u16*)(ws + 197132288);    //  90,177,536  Wd bf16 [4096][11008]
  u16*  actb = (u16*)(ws + 287309824);    //  45,088,768  sg / act bf16 [2048][11008]
  float* tg  = (float*)(ws + 332398592);  //  131,072
  float* tu  = (float*)(ws + 332529664);  //  131,072
  float* td  = (float*)(ws + 332660736);  //  131,072

  cvt_kernel<<<1024, 256, 0, stream>>>((const float4*)x,  (ushort4*)xb,  8388608 / 4);
  cvt_kernel<<<2048, 256, 0, stream>>>((const float4*)Wg, (ushort4*)wgb, 45088768 / 4);
  cvt_kernel<<<2048, 256, 0, stream>>>((const float4*)Wu, (ushort4*)wub, 45088768 / 4);
  cvt_kernel<<<2048, 256, 0, stream>>>((const float4*)Wd, (ushort4*)wdb, 45088768 / 4);

  lora_t_kernel<<<32, 256, 0, stream>>>(xb, 4096, Ag, Au, lidx, lay, tg, tu);

  gemm_gu<0><<<dim3(16, 86), 256, 0, stream>>>(xb, wgb, tg, Bg, lidx, lay, actb);
  gemm_gu<1><<<dim3(16, 86), 256, 0, stream>>>(xb, wub, tu, Bu, lidx, lay, actb);

  lora_t_kernel<<<32, 256, 0, stream>>>(actb, 11008, Ad, nullptr, lidx, lay, td, nullptr);

  gemm_down<<<dim3(16, 32), 256, 0, stream>>>(actb, wdb, td, Bd, lidx, lay, out);
}

// Round 3
// 1250.732 us; speedup vs baseline: 2.2141x; 1.9030x over previous
//
#include <hip/hip_runtime.h>
#include <hip/hip_bf16.h>

typedef __bf16 bf16x8 __attribute__((ext_vector_type(8)));
typedef float  f32x4  __attribute__((ext_vector_type(4)));
typedef unsigned short u16;

#define GLDS16(gsrc, ldst)                                                        \
  __builtin_amdgcn_global_load_lds(                                               \
      (const __attribute__((address_space(1))) unsigned int*)(gsrc),              \
      (__attribute__((address_space(3))) unsigned int*)(ldst), 16, 0, 0)

__device__ __forceinline__ u16 f2b(float f) {
  unsigned int u = __builtin_bit_cast(unsigned int, f);
  u = (u + 0x7fffu + ((u >> 16) & 1u)) >> 16;
  return (u16)u;
}
__device__ __forceinline__ float b2f(u16 b) {
  unsigned int u = ((unsigned int)b) << 16;
  return __builtin_bit_cast(float, u);
}

// ---------------- fp32 -> bf16 convert (vectorized, grid-stride) ----------------
__global__ __launch_bounds__(256) void cvt_kernel(const float4* __restrict__ in,
                                                  ushort4* __restrict__ out, int n4) {
  int i = blockIdx.x * blockDim.x + threadIdx.x;
  int stride = gridDim.x * blockDim.x;
  for (; i < n4; i += stride) {
    float4 v = in[i];
    ushort4 o;
    o.x = f2b(v.x); o.y = f2b(v.y); o.z = f2b(v.z); o.w = f2b(v.w);
    out[i] = o;
  }
}

// ------ LoRA rank-projection: t_bf16[m][r] = 0.5 * sum_k Xb[m][k] * A[r][k] -----
__global__ __launch_bounds__(256) void lora_t_kernel(const u16* __restrict__ Xb, int K,
                                                     const float* __restrict__ A1,
                                                     const float* __restrict__ A2,
                                                     const int* __restrict__ lidx,
                                                     const int* __restrict__ layer,
                                                     u16* __restrict__ t1,
                                                     u16* __restrict__ t2) {
  const int lane = threadIdx.x & 63, wid = threadIdx.x >> 6;
  const int m0 = blockIdx.x * 64 + wid * 16;
  const int li = lidx[m0 >> 9];
  const size_t abase = ((size_t)layer[0] * 16 + li) * 16 * (size_t)K;
  const int r = lane & 15, kg = lane >> 4;
  f32x4 acc1 = {0.f, 0.f, 0.f, 0.f}, acc2 = {0.f, 0.f, 0.f, 0.f};
  for (int k0 = 0; k0 < K; k0 += 32) {
    bf16x8 a = *(const bf16x8*)&Xb[(size_t)(m0 + r) * K + k0 + kg * 8];
    const float* ap = A1 + abase + (size_t)r * K + k0 + kg * 8;
    float4 f0 = *(const float4*)ap;
    float4 f1 = *(const float4*)(ap + 4);
    bf16x8 b;
    b[0] = (__bf16)f0.x; b[1] = (__bf16)f0.y; b[2] = (__bf16)f0.z; b[3] = (__bf16)f0.w;
    b[4] = (__bf16)f1.x; b[5] = (__bf16)f1.y; b[6] = (__bf16)f1.z; b[7] = (__bf16)f1.w;
    acc1 = __builtin_amdgcn_mfma_f32_16x16x32_bf16(a, b, acc1, 0, 0, 0);
    if (A2) {
      const float* ap2 = A2 + abase + (size_t)r * K + k0 + kg * 8;
      float4 g0 = *(const float4*)ap2;
      float4 g1 = *(const float4*)(ap2 + 4);
      bf16x8 b2;
      b2[0] = (__bf16)g0.x; b2[1] = (__bf16)g0.y; b2[2] = (__bf16)g0.z; b2[3] = (__bf16)g0.w;
      b2[4] = (__bf16)g1.x; b2[5] = (__bf16)g1.y; b2[6] = (__bf16)g1.z; b2[7] = (__bf16)g1.w;
      acc2 = __builtin_amdgcn_mfma_f32_16x16x32_bf16(a, b2, acc2, 0, 0, 0);
    }
  }
#pragma unroll
  for (int j = 0; j < 4; ++j) {
    int m = m0 + (lane >> 4) * 4 + j;
    t1[(size_t)m * 16 + (lane & 15)] = f2b(0.5f * acc1[j]);
    if (A2) t2[(size_t)m * 16 + (lane & 15)] = f2b(0.5f * acc2[j]);
  }
}

// ---------------- gate / up GEMM (128x128 tile, BK=64, 4 waves 2x2) -------------
// LoRA folded into acc via one extra MFMA per fragment (K=16 zero-padded to 32).
// IS_UP=0: sg = silu(Xb.Wg^T + tb.Bg^T)            (write bf16)
// IS_UP=1: act = sg * (Xb.Wu^T + tb.Bu^T)          (in-place over sg)
template <int IS_UP>
__global__ __launch_bounds__(256, 3) void gemm_gu(
    const u16* __restrict__ Xb, const u16* __restrict__ W,
    const u16* __restrict__ tb, const float* __restrict__ Bw,
    const int* __restrict__ lidx, const int* __restrict__ layer,
    u16* __restrict__ io) {
  constexpr int K = 4096, F = 11008;
  __shared__ alignas(16) u16 lA[128 * 64];
  __shared__ alignas(16) u16 lB[128 * 64];
  const int tid = threadIdx.x, lane = tid & 63, wid = tid >> 6;
  const int wr = wid >> 1, wc = wid & 1;
  const int m0 = blockIdx.x * 128, n0 = blockIdx.y * 128;
  const int lr = lane & 15, kg = lane >> 4;

  f32x4 acc[4][4] = {};

  for (int k0 = 0; k0 < K; k0 += 64) {
#pragma unroll
    for (int i = 0; i < 4; ++i) {
      int e = wid * 2048 + i * 512 + lane * 8;
      int row = e >> 6, col = e & 63;
      int ldso = wid * 2048 + i * 512;
      GLDS16(Xb + (size_t)(m0 + row) * K + k0 + col, &lA[ldso]);
      GLDS16(W + (size_t)(n0 + row) * K + k0 + col, &lB[ldso]);
    }
    __syncthreads();
#pragma unroll
    for (int kk = 0; kk < 2; ++kk) {
      bf16x8 a[4], b[4];
#pragma unroll
      for (int mi = 0; mi < 4; ++mi)
        a[mi] = *(const bf16x8*)&lA[(wr * 64 + mi * 16 + lr) * 64 + kk * 32 + kg * 8];
#pragma unroll
      for (int ni = 0; ni < 4; ++ni)
        b[ni] = *(const bf16x8*)&lB[(wc * 64 + ni * 16 + lr) * 64 + kk * 32 + kg * 8];
#pragma unroll
      for (int mi = 0; mi < 4; ++mi)
#pragma unroll
        for (int ni = 0; ni < 4; ++ni)
          acc[mi][ni] = __builtin_amdgcn_mfma_f32_16x16x32_bf16(a[mi], b[ni], acc[mi][ni], 0, 0, 0);
    }
    __syncthreads();
  }

  // ---- LoRA via MFMA: acc += t(0.5-scaled, bf16) @ B^T, K=16 padded to 32 ----
  const int li = lidx[m0 >> 9];
  const size_t bbase = ((size_t)layer[0] * 16 + li) * (size_t)F * 16;
  bf16x8 la[4], lb[4];
  const bf16x8 zz = {};
#pragma unroll
  for (int mi = 0; mi < 4; ++mi) {
    int row = m0 + wr * 64 + mi * 16 + lr;
    la[mi] = (kg < 2) ? *(const bf16x8*)&tb[(size_t)row * 16 + kg * 8] : zz;
  }
#pragma unroll
  for (int ni = 0; ni < 4; ++ni) {
    int col = n0 + wc * 64 + ni * 16 + lr;
    if (kg < 2) {
      const float* bp = Bw + bbase + (size_t)col * 16 + kg * 8;
      float4 f0 = *(const float4*)bp;
      float4 f1 = *(const float4*)(bp + 4);
      bf16x8 v;
      v[0] = (__bf16)f0.x; v[1] = (__bf16)f0.y; v[2] = (__bf16)f0.z; v[3] = (__bf16)f0.w;
      v[4] = (__bf16)f1.x; v[5] = (__bf16)f1.y; v[6] = (__bf16)f1.z; v[7] = (__bf16)f1.w;
      lb[ni] = v;
    } else lb[ni] = zz;
  }
#pragma unroll
  for (int mi = 0; mi < 4; ++mi)
#pragma unroll
    for (int ni = 0; ni < 4; ++ni)
      acc[mi][ni] = __builtin_amdgcn_mfma_f32_16x16x32_bf16(la[mi], lb[ni], acc[mi][ni], 0, 0, 0);

  // ---- store: silu (gate pass) or multiply-in-place (up pass) ----
#pragma unroll
  for (int ni = 0; ni < 4; ++ni) {
    int c = wc * 64 + ni * 16 + lr;
#pragma unroll
    for (int mi = 0; mi < 4; ++mi) {
#pragma unroll
      for (int j = 0; j < 4; ++j) {
        int r_ = wr * 64 + mi * 16 + kg * 4 + j;
        float v = acc[mi][ni][j];
        size_t oidx = (size_t)(m0 + r_) * F + (n0 + c);
        if (IS_UP) {
          float g = b2f(io[oidx]);
          io[oidx] = f2b(g * v);
        } else {
          float s = v / (1.f + __expf(-v));
          io[oidx] = f2b(s);
        }
      }
    }
  }
}

// ---------------- down GEMM + LoRA(MFMA) -> out fp32 ----------------
__global__ __launch_bounds__(256, 3) void gemm_down(
    const u16* __restrict__ Ab, const u16* __restrict__ Wd,
    const u16* __restrict__ tb, const float* __restrict__ Bd,
    const int* __restrict__ lidx, const int* __restrict__ layer,
    float* __restrict__ out) {
  constexpr int K = 11008, H = 4096;
  __shared__ alignas(16) u16 lA[128 * 64];
  __shared__ alignas(16) u16 lB[128 * 64];
  const int tid = threadIdx.x, lane = tid & 63, wid = tid >> 6;
  const int wr = wid >> 1, wc = wid & 1;
  const int m0 = blockIdx.x * 128, n0 = blockIdx.y * 128;
  const int lr = lane & 15, kg = lane >> 4;

  f32x4 acc[4][4] = {};

  for (int k0 = 0; k0 < K; k0 += 64) {
#pragma unroll
    for (int i = 0; i < 4; ++i) {
      int e = wid * 2048 + i * 512 + lane * 8;
      int row = e >> 6, col = e & 63;
      int ldso = wid * 2048 + i * 512;
      GLDS16(Ab + (size_t)(m0 + row) * K + k0 + col, &lA[ldso]);
      GLDS16(Wd + (size_t)(n0 + row) * K + k0 + col, &lB[ldso]);
    }
    __syncthreads();
#pragma unroll
    for (int kk = 0; kk < 2; ++kk) {
      bf16x8 a[4], b[4];
#pragma unroll
      for (int mi = 0; mi < 4; ++mi)
        a[mi] = *(const bf16x8*)&lA[(wr * 64 + mi * 16 + lr) * 64 + kk * 32 + kg * 8];
#pragma unroll
      for (int ni = 0; ni < 4; ++ni)
        b[ni] = *(const bf16x8*)&lB[(wc * 64 + ni * 16 + lr) * 64 + kk * 32 + kg * 8];
#pragma unroll
      for (int mi = 0; mi < 4; ++mi)
#pragma unroll
        for (int ni = 0; ni < 4; ++ni)
          acc[mi][ni] = __builtin_amdgcn_mfma_f32_16x16x32_bf16(a[mi], b[ni], acc[mi][ni], 0, 0, 0);
    }
    __syncthreads();
  }

  const int li = lidx[m0 >> 9];
  const size_t bbase = ((size_t)layer[0] * 16 + li) * (size_t)H * 16;
  bf16x8 la[4], lb[4];
  const bf16x8 zz = {};
#pragma unroll
  for (int mi = 0; mi < 4; ++mi) {
    int row = m0 + wr * 64 + mi * 16 + lr;
    la[mi] = (kg < 2) ? *(const bf16x8*)&tb[(size_t)row * 16 + kg * 8] : zz;
  }
#pragma unroll
  for (int ni = 0; ni < 4; ++ni) {
    int col = n0 + wc * 64 + ni * 16 + lr;
    if (kg < 2) {
      const float* bp = Bd + bbase + (size_t)col * 16 + kg * 8;
      float4 f0 = *(const float4*)bp;
      float4 f1 = *(const float4*)(bp + 4);
      bf16x8 v;
      v[0] = (__bf16)f0.x; v[1] = (__bf16)f0.y; v[2] = (__bf16)f0.z; v[3] = (__bf16)f0.w;
      v[4] = (__bf16)f1.x; v[5] = (__bf16)f1.y; v[6] = (__bf16)f1.z; v[7] = (__bf16)f1.w;
      lb[ni] = v;
    } else lb[ni] = zz;
  }
#pragma unroll
  for (int mi = 0; mi < 4; ++mi)
#pragma unroll
    for (int ni = 0; ni < 4; ++ni)
      acc[mi][ni] = __builtin_amdgcn_mfma_f32_16x16x32_bf16(la[mi], lb[ni], acc[mi][ni], 0, 0, 0);

#pragma unroll
  for (int ni = 0; ni < 4; ++ni) {
    int c = wc * 64 + ni * 16 + lr;
#pragma unroll
    for (int mi = 0; mi < 4; ++mi) {
#pragma unroll
      for (int j = 0; j < 4; ++j) {
        int r_ = wr * 64 + mi * 16 + kg * 4 + j;
        out[(size_t)(m0 + r_) * H + (n0 + c)] = acc[mi][ni][j];
      }
    }
  }
}

extern "C" void kernel_launch(void* const* d_in, const int* in_sizes, int n_in,
                              void* d_out, int out_size, void* d_ws, size_t ws_size,
                              hipStream_t stream) {
  const float* x  = (const float*)d_in[0];
  const float* Wg = (const float*)d_in[1];
  const float* Wu = (const float*)d_in[2];
  const float* Wd = (const float*)d_in[3];
  const float* Ag = (const float*)d_in[4];
  const float* Bg = (const float*)d_in[5];
  const float* Au = (const float*)d_in[6];
  const float* Bu = (const float*)d_in[7];
  const float* Ad = (const float*)d_in[8];
  const float* Bd = (const float*)d_in[9];
  const int* lidx = (const int*)d_in[10];
  const int* lay  = (const int*)d_in[11];
  float* out = (float*)d_out;

  // ws layout (bytes)
  char* ws = (char*)d_ws;
  u16*  xb   = (u16*)(ws + 0);            //  16,777,216  x bf16 [2048][4096]
  u16*  wgb  = (u16*)(ws + 16777216);     //  90,177,536  Wg bf16 [11008][4096]
  u16*  wub  = (u16*)(ws + 106954752);    //  90,177,536  Wu bf16
  u16*  wdb  = (u16*)(ws + 197132288);    //  90,177,536  Wd bf16 [4096][11008]
  u16*  actb = (u16*)(ws + 287309824);    //  45,088,768  sg / act bf16 [2048][11008]
  u16*  tg   = (u16*)(ws + 332398592);    //  65,536  t bf16 (0.5-scaled)
  u16*  tu   = (u16*)(ws + 332529664);    //  65,536
  u16*  td   = (u16*)(ws + 332660736);    //  65,536

  cvt_kernel<<<1024, 256, 0, stream>>>((const float4*)x,  (ushort4*)xb,  8388608 / 4);
  cvt_kernel<<<2048, 256, 0, stream>>>((const float4*)Wg, (ushort4*)wgb, 45088768 / 4);
  cvt_kernel<<<2048, 256, 0, stream>>>((const float4*)Wu, (ushort4*)wub, 45088768 / 4);
  cvt_kernel<<<2048, 256, 0, stream>>>((const float4*)Wd, (ushort4*)wdb, 45088768 / 4);

  lora_t_kernel<<<32, 256, 0, stream>>>(xb, 4096, Ag, Au, lidx, lay, tg, tu);

  gemm_gu<0><<<dim3(16, 86), 256, 0, stream>>>(xb, wgb, tg, Bg, lidx, lay, actb);
  gemm_gu<1><<<dim3(16, 86), 256, 0, stream>>>(xb, wub, tu, Bu, lidx, lay, actb);

  lora_t_kernel<<<32, 256, 0, stream>>>(actb, 11008, Ad, nullptr, lidx, lay, td, nullptr);

  gemm_down<<<dim3(16, 32), 256, 0, stream>>>(actb, wdb, td, Bd, lidx, lay, out);
}

// Round 4
// 1100.281 us; speedup vs baseline: 2.5168x; 1.1367x over previous
//
#include <hip/hip_runtime.h>
#include <hip/hip_bf16.h>

typedef __bf16 bf16x8 __attribute__((ext_vector_type(8)));
typedef float  f32x4  __attribute__((ext_vector_type(4)));
typedef unsigned short u16;

#define GLDS16(gsrc, ldst)                                                        \
  __builtin_amdgcn_global_load_lds(                                               \
      (const __attribute__((address_space(1))) unsigned int*)(gsrc),              \
      (__attribute__((address_space(3))) unsigned int*)(ldst), 16, 0, 0)

#define BAR() __builtin_amdgcn_s_barrier()
#define WAIT_LGKM0() asm volatile("s_waitcnt lgkmcnt(0)" ::: "memory")
#define WAIT_VM4() asm volatile("s_waitcnt vmcnt(4)" ::: "memory")

__device__ __forceinline__ u16 f2b(float f) {
  unsigned int u = __builtin_bit_cast(unsigned int, f);
  u = (u + 0x7fffu + ((u >> 16) & 1u)) >> 16;
  return (u16)u;
}
__device__ __forceinline__ float b2f(u16 b) {
  unsigned int u = ((unsigned int)b) << 16;
  return __builtin_bit_cast(float, u);
}

// ---------------- fp32 -> bf16 convert ----------------
__global__ __launch_bounds__(256) void cvt_kernel(const float4* __restrict__ in,
                                                  ushort4* __restrict__ out, int n4) {
  int i = blockIdx.x * blockDim.x + threadIdx.x;
  int stride = gridDim.x * blockDim.x;
  for (; i < n4; i += stride) {
    float4 v = in[i];
    ushort4 o;
    o.x = f2b(v.x); o.y = f2b(v.y); o.z = f2b(v.z); o.w = f2b(v.w);
    out[i] = o;
  }
}

// ------ LoRA rank-projection: t_bf16[m][r] = 0.5 * sum_k Xb[m][k] * A[r][k] -----
__global__ __launch_bounds__(256) void lora_t_kernel(const u16* __restrict__ Xb, int K,
                                                     const float* __restrict__ A1,
                                                     const float* __restrict__ A2,
                                                     const int* __restrict__ lidx,
                                                     const int* __restrict__ layer,
                                                     u16* __restrict__ t1,
                                                     u16* __restrict__ t2) {
  const int lane = threadIdx.x & 63, wid = threadIdx.x >> 6;
  const int m0 = blockIdx.x * 64 + wid * 16;
  const int li = lidx[m0 >> 9];
  const size_t abase = ((size_t)layer[0] * 16 + li) * 16 * (size_t)K;
  const int r = lane & 15, kg = lane >> 4;
  f32x4 acc1 = {0.f, 0.f, 0.f, 0.f}, acc2 = {0.f, 0.f, 0.f, 0.f};
  for (int k0 = 0; k0 < K; k0 += 32) {
    bf16x8 a = *(const bf16x8*)&Xb[(size_t)(m0 + r) * K + k0 + kg * 8];
    const float* ap = A1 + abase + (size_t)r * K + k0 + kg * 8;
    float4 f0 = *(const float4*)ap;
    float4 f1 = *(const float4*)(ap + 4);
    bf16x8 b;
    b[0] = (__bf16)f0.x; b[1] = (__bf16)f0.y; b[2] = (__bf16)f0.z; b[3] = (__bf16)f0.w;
    b[4] = (__bf16)f1.x; b[5] = (__bf16)f1.y; b[6] = (__bf16)f1.z; b[7] = (__bf16)f1.w;
    acc1 = __builtin_amdgcn_mfma_f32_16x16x32_bf16(a, b, acc1, 0, 0, 0);
    if (A2) {
      const float* ap2 = A2 + abase + (size_t)r * K + k0 + kg * 8;
      float4 g0 = *(const float4*)ap2;
      float4 g1 = *(const float4*)(ap2 + 4);
      bf16x8 b2;
      b2[0] = (__bf16)g0.x; b2[1] = (__bf16)g0.y; b2[2] = (__bf16)g0.z; b2[3] = (__bf16)g0.w;
      b2[4] = (__bf16)g1.x; b2[5] = (__bf16)g1.y; b2[6] = (__bf16)g1.z; b2[7] = (__bf16)g1.w;
      acc2 = __builtin_amdgcn_mfma_f32_16x16x32_bf16(a, b2, acc2, 0, 0, 0);
    }
  }
#pragma unroll
  for (int j = 0; j < 4; ++j) {
    int m = m0 + (lane >> 4) * 4 + j;
    t1[(size_t)m * 16 + (lane & 15)] = f2b(0.5f * acc1[j]);
    if (A2) t2[(size_t)m * 16 + (lane & 15)] = f2b(0.5f * acc2[j]);
  }
}

// ================= 8-phase 256x256 fused gate|up GEMM =================
// Grid (8, 86): by<43 -> gate (write gout), by>=43 -> up (write uout).
// 512 thr = 8 waves (2M x 4N), per-wave C = 128x64, BK=64, dbuf LDS 128KB.
// LDS XOR swizzle: 16B-slot s at row r stored at slot s^(r&7); both sides.
#define STAGE(buf, half, kt) do {                                              \
    int r0_ = ((half) & 1) * 128;                                              \
    const u16* gs_ = ((half) < 2)                                              \
        ? (Xb + (size_t)(m0 + r0_) * 4096 + (size_t)(kt) * 64)                 \
        : (W + (size_t)(n0 + r0_) * 4096 + (size_t)(kt) * 64);                 \
    u16* ld_ = (((half) < 2) ? sA : sB) + (buf) * 16384 + r0_ * 64;            \
    _Pragma("unroll")                                                          \
    for (int i_ = 0; i_ < 2; ++i_) {                                           \
      int ub_ = (wid << 6) + i_ * 512;                                         \
      int un_ = ub_ + lane;                                                    \
      int ur_ = un_ >> 3, us_ = (un_ & 7) ^ (ur_ & 7);                         \
      GLDS16(gs_ + (size_t)ur_ * 4096 + us_ * 8, ld_ + ub_ * 8);               \
    }                                                                          \
  } while (0)

#define RD_A(dst, buf, mh) do {                                                \
    _Pragma("unroll")                                                          \
    for (int mf_ = 0; mf_ < 4; ++mf_)                                          \
      _Pragma("unroll")                                                        \
      for (int ks_ = 0; ks_ < 2; ++ks_) {                                      \
        int row_ = wm * 128 + (mh) * 64 + mf_ * 16 + lr;                       \
        int sl_ = (ks_ * 4 + kg) ^ rx;                                         \
        dst[mf_][ks_] = *(const bf16x8*)&sA[(buf) * 16384 + row_ * 64 + sl_ * 8]; \
      }                                                                        \
  } while (0)

#define RD_B(dst, buf, nh) do {                                                \
    _Pragma("unroll")                                                          \
    for (int nf_ = 0; nf_ < 2; ++nf_)                                          \
      _Pragma("unroll")                                                        \
      for (int ks_ = 0; ks_ < 2; ++ks_) {                                      \
        int row_ = wn * 64 + (nh) * 32 + nf_ * 16 + lr;                        \
        int sl_ = (ks_ * 4 + kg) ^ rx;                                         \
        dst[nf_][ks_] = *(const bf16x8*)&sB[(buf) * 16384 + row_ * 64 + sl_ * 8]; \
      }                                                                        \
  } while (0)

#define MMA_Q(AF, BF, mb, nb) do {                                             \
    __builtin_amdgcn_s_setprio(1);                                             \
    _Pragma("unroll")                                                          \
    for (int mf_ = 0; mf_ < 4; ++mf_)                                          \
      _Pragma("unroll")                                                        \
      for (int nf_ = 0; nf_ < 2; ++nf_)                                        \
        _Pragma("unroll")                                                      \
        for (int ks_ = 0; ks_ < 2; ++ks_)                                      \
          acc[(mb) + mf_][(nb) + nf_] = __builtin_amdgcn_mfma_f32_16x16x32_bf16( \
              AF[mf_][ks_], BF[nf_][ks_], acc[(mb) + mf_][(nb) + nf_], 0, 0, 0); \
    __builtin_amdgcn_s_setprio(0);                                             \
  } while (0)

__global__ __launch_bounds__(512, 2) void gemm_gup8(
    const u16* __restrict__ Xb, const u16* __restrict__ Wg, const u16* __restrict__ Wu,
    const u16* __restrict__ tg, const u16* __restrict__ tu,
    const float* __restrict__ Bg, const float* __restrict__ Bu,
    const int* __restrict__ lidx, const int* __restrict__ layer,
    u16* __restrict__ gout, u16* __restrict__ uout) {
  constexpr int F = 11008;
  extern __shared__ u16 smem[];
  u16* sA = smem;            // [2][256*64]
  u16* sB = smem + 32768;    // [2][256*64]
  const int tid = threadIdx.x, lane = tid & 63, wid = tid >> 6;
  const int lr = lane & 15, kg = lane >> 4, rx = lr & 7;
  const int wm = wid >> 2, wn = wid & 3;
  const bool isUp = blockIdx.y >= 43;
  const int m0 = blockIdx.x * 256;
  const int n0 = (isUp ? blockIdx.y - 43 : blockIdx.y) * 256;
  const u16* W = isUp ? Wu : Wg;
  const u16* tb = isUp ? tu : tg;
  const float* Bw = isUp ? Bu : Bg;
  u16* ob = isUp ? uout : gout;

  f32x4 acc[8][4] = {};
  bf16x8 a0[4][2], a1[4][2], b0[2][2], b1[2][2];

  // prologue: tile0 -> buf0 (A,B), tile1 B -> buf1; tile1 A staged at iter0 g1/g2
  STAGE(0, 0, 0); STAGE(0, 1, 0); STAGE(0, 2, 0); STAGE(0, 3, 0);
  STAGE(1, 2, 1); STAGE(1, 3, 1);
  WAIT_VM4(); BAR();

#pragma unroll 1
  for (int u = 0; u < 32; ++u) {
    const int ktA = (2 * u + 1) & 63;
    const int kt0 = (2 * u + 2) & 63;
    const int kt1 = (2 * u + 3) & 63;
    // g1: read buf0 A-mh0 + B-nh0; stage buf1 A-lo (tile 2u+1)
    RD_A(a0, 0, 0); RD_B(b0, 0, 0);
    STAGE(1, 0, ktA);
    BAR(); WAIT_LGKM0();
    MMA_Q(a0, b0, 0, 0);
    BAR();
    // g2
    RD_B(b1, 0, 1);
    STAGE(1, 1, ktA);
    BAR(); WAIT_LGKM0();
    MMA_Q(a0, b1, 0, 2);
    BAR();
    // g3
    RD_A(a1, 0, 1);
    STAGE(0, 2, kt0);
    BAR(); WAIT_LGKM0();
    MMA_Q(a1, b1, 4, 2);
    BAR();
    // g4 (vmcnt before closing barrier: buf1 A/B guaranteed landed for g5)
    STAGE(0, 3, kt0);
    BAR();
    MMA_Q(a1, b0, 4, 0);
    WAIT_VM4();
    BAR();
    // g5: compute buf1 (tile 2u+1); stage buf0 A-lo (tile 2u+2)
    RD_A(a0, 1, 0); RD_B(b0, 1, 0);
    STAGE(0, 0, kt0);
    BAR(); WAIT_LGKM0();
    MMA_Q(a0, b0, 0, 0);
    BAR();
    // g6
    RD_B(b1, 1, 1);
    STAGE(0, 1, kt0);
    BAR(); WAIT_LGKM0();
    MMA_Q(a0, b1, 0, 2);
    BAR();
    // g7
    RD_A(a1, 1, 1);
    STAGE(1, 2, kt1);
    BAR(); WAIT_LGKM0();
    MMA_Q(a1, b1, 4, 2);
    BAR();
    // g8
    STAGE(1, 3, kt1);
    BAR();
    MMA_Q(a1, b0, 4, 0);
    WAIT_VM4();
    BAR();
  }

  // ---- LoRA via MFMA (K=16 padded to 32), then bf16 store ----
  const int li = lidx[m0 >> 9];
  const size_t bbase = ((size_t)layer[0] * 16 + li) * (size_t)F * 16;
  bf16x8 la[8], lb[4];
  const bf16x8 zz = {};
#pragma unroll
  for (int mf = 0; mf < 8; ++mf) {
    int row = m0 + wm * 128 + mf * 16 + lr;
    la[mf] = (kg < 2) ? *(const bf16x8*)&tb[(size_t)row * 16 + kg * 8] : zz;
  }
#pragma unroll
  for (int nf = 0; nf < 4; ++nf) {
    int col = n0 + wn * 64 + nf * 16 + lr;
    if (kg < 2) {
      const float* bp = Bw + bbase + (size_t)col * 16 + kg * 8;
      float4 f0 = *(const float4*)bp;
      float4 f1 = *(const float4*)(bp + 4);
      bf16x8 v;
      v[0] = (__bf16)f0.x; v[1] = (__bf16)f0.y; v[2] = (__bf16)f0.z; v[3] = (__bf16)f0.w;
      v[4] = (__bf16)f1.x; v[5] = (__bf16)f1.y; v[6] = (__bf16)f1.z; v[7] = (__bf16)f1.w;
      lb[nf] = v;
    } else lb[nf] = zz;
  }
#pragma unroll
  for (int mf = 0; mf < 8; ++mf)
#pragma unroll
    for (int nf = 0; nf < 4; ++nf)
      acc[mf][nf] = __builtin_amdgcn_mfma_f32_16x16x32_bf16(la[mf], lb[nf], acc[mf][nf], 0, 0, 0);

#pragma unroll
  for (int mf = 0; mf < 8; ++mf)
#pragma unroll
    for (int nf = 0; nf < 4; ++nf)
#pragma unroll
      for (int j = 0; j < 4; ++j) {
        int row = m0 + wm * 128 + mf * 16 + kg * 4 + j;
        int col = n0 + wn * 64 + nf * 16 + lr;
        ob[(size_t)row * F + col] = f2b(acc[mf][nf][j]);
      }
}

// ---------------- swiglu: g = silu(g) * u (bf16, 8 elems/thread) ----------------
__global__ __launch_bounds__(256) void swiglu_kernel(uint4* __restrict__ g,
                                                     const uint4* __restrict__ u, int n) {
  int i = blockIdx.x * 256 + threadIdx.x, st = gridDim.x * 256;
  for (; i < n; i += st) {
    uint4 gv = g[i], uv = u[i], ov;
    unsigned* gw = (unsigned*)&gv;
    unsigned* uw = (unsigned*)&uv;
    unsigned* ow = (unsigned*)&ov;
#pragma unroll
    for (int q = 0; q < 4; ++q) {
      float g0 = __builtin_bit_cast(float, gw[q] << 16);
      float g1 = __builtin_bit_cast(float, gw[q] & 0xffff0000u);
      float u0 = __builtin_bit_cast(float, uw[q] << 16);
      float u1 = __builtin_bit_cast(float, uw[q] & 0xffff0000u);
      float a0 = g0 / (1.f + __expf(-g0)) * u0;
      float a1 = g1 / (1.f + __expf(-g1)) * u1;
      ow[q] = (unsigned)f2b(a0) | ((unsigned)f2b(a1) << 16);
    }
    g[i] = ov;
  }
}

// ---------------- down GEMM (2-phase 128^2) + LoRA(MFMA) -> out fp32 ----------------
__global__ __launch_bounds__(256, 3) void gemm_down(
    const u16* __restrict__ Ab, const u16* __restrict__ Wd,
    const u16* __restrict__ tb, const float* __restrict__ Bd,
    const int* __restrict__ lidx, const int* __restrict__ layer,
    float* __restrict__ out) {
  constexpr int K = 11008, H = 4096;
  __shared__ alignas(16) u16 lA[128 * 64];
  __shared__ alignas(16) u16 lB[128 * 64];
  const int tid = threadIdx.x, lane = tid & 63, wid = tid >> 6;
  const int wr = wid >> 1, wc = wid & 1;
  const int m0 = blockIdx.x * 128, n0 = blockIdx.y * 128;
  const int lr = lane & 15, kg = lane >> 4;

  f32x4 acc[4][4] = {};

  for (int k0 = 0; k0 < K; k0 += 64) {
#pragma unroll
    for (int i = 0; i < 4; ++i) {
      int e = wid * 2048 + i * 512 + lane * 8;
      int row = e >> 6, col = e & 63;
      int ldso = wid * 2048 + i * 512;
      GLDS16(Ab + (size_t)(m0 + row) * K + k0 + col, &lA[ldso]);
      GLDS16(Wd + (size_t)(n0 + row) * K + k0 + col, &lB[ldso]);
    }
    __syncthreads();
#pragma unroll
    for (int kk = 0; kk < 2; ++kk) {
      bf16x8 a[4], b[4];
#pragma unroll
      for (int mi = 0; mi < 4; ++mi)
        a[mi] = *(const bf16x8*)&lA[(wr * 64 + mi * 16 + lr) * 64 + kk * 32 + kg * 8];
#pragma unroll
      for (int ni = 0; ni < 4; ++ni)
        b[ni] = *(const bf16x8*)&lB[(wc * 64 + ni * 16 + lr) * 64 + kk * 32 + kg * 8];
#pragma unroll
      for (int mi = 0; mi < 4; ++mi)
#pragma unroll
        for (int ni = 0; ni < 4; ++ni)
          acc[mi][ni] = __builtin_amdgcn_mfma_f32_16x16x32_bf16(a[mi], b[ni], acc[mi][ni], 0, 0, 0);
    }
    __syncthreads();
  }

  const int li = lidx[m0 >> 9];
  const size_t bbase = ((size_t)layer[0] * 16 + li) * (size_t)H * 16;
  bf16x8 la[4], lb[4];
  const bf16x8 zz = {};
#pragma unroll
  for (int mi = 0; mi < 4; ++mi) {
    int row = m0 + wr * 64 + mi * 16 + lr;
    la[mi] = (kg < 2) ? *(const bf16x8*)&tb[(size_t)row * 16 + kg * 8] : zz;
  }
#pragma unroll
  for (int ni = 0; ni < 4; ++ni) {
    int col = n0 + wc * 64 + ni * 16 + lr;
    if (kg < 2) {
      const float* bp = Bd + bbase + (size_t)col * 16 + kg * 8;
      float4 f0 = *(const float4*)bp;
      float4 f1 = *(const float4*)(bp + 4);
      bf16x8 v;
      v[0] = (__bf16)f0.x; v[1] = (__bf16)f0.y; v[2] = (__bf16)f0.z; v[3] = (__bf16)f0.w;
      v[4] = (__bf16)f1.x; v[5] = (__bf16)f1.y; v[6] = (__bf16)f1.z; v[7] = (__bf16)f1.w;
      lb[ni] = v;
    } else lb[ni] = zz;
  }
#pragma unroll
  for (int mi = 0; mi < 4; ++mi)
#pragma unroll
    for (int ni = 0; ni < 4; ++ni)
      acc[mi][ni] = __builtin_amdgcn_mfma_f32_16x16x32_bf16(la[mi], lb[ni], acc[mi][ni], 0, 0, 0);

#pragma unroll
  for (int ni = 0; ni < 4; ++ni) {
    int c = wc * 64 + ni * 16 + lr;
#pragma unroll
    for (int mi = 0; mi < 4; ++mi) {
#pragma unroll
      for (int j = 0; j < 4; ++j) {
        int r_ = wr * 64 + mi * 16 + kg * 4 + j;
        out[(size_t)(m0 + r_) * H + (n0 + c)] = acc[mi][ni][j];
      }
    }
  }
}

extern "C" void kernel_launch(void* const* d_in, const int* in_sizes, int n_in,
                              void* d_out, int out_size, void* d_ws, size_t ws_size,
                              hipStream_t stream) {
  const float* x  = (const float*)d_in[0];
  const float* Wg = (const float*)d_in[1];
  const float* Wu = (const float*)d_in[2];
  const float* Wd = (const float*)d_in[3];
  const float* Ag = (const float*)d_in[4];
  const float* Bg = (const float*)d_in[5];
  const float* Au = (const float*)d_in[6];
  const float* Bu = (const float*)d_in[7];
  const float* Ad = (const float*)d_in[8];
  const float* Bd = (const float*)d_in[9];
  const int* lidx = (const int*)d_in[10];
  const int* lay  = (const int*)d_in[11];
  float* out = (float*)d_out;

  // ws layout (bytes); wdb2 reuses wgb's slot after the gate/up GEMM is done.
  char* ws = (char*)d_ws;
  u16*  xb   = (u16*)(ws + 0);            //  16,777,216  x bf16 [2048][4096]
  u16*  wgb  = (u16*)(ws + 16777216);     //  90,177,536  Wg bf16 [11008][4096]
  u16*  wub  = (u16*)(ws + 106954752);    //  90,177,536  Wu bf16
  u16*  gbuf = (u16*)(ws + 197132288);    //  45,088,768  gate -> act bf16 [2048][11008]
  u16*  ubuf = (u16*)(ws + 242221056);    //  45,088,768  up bf16
  u16*  tg   = (u16*)(ws + 287309824);    //  65,536
  u16*  tu   = (u16*)(ws + 287375360);    //  65,536
  u16*  td   = (u16*)(ws + 287440896);    //  65,536
  u16*  wdb2 = wgb;                       //  Wd bf16 [4096][11008] (after gup8)

  hipFuncSetAttribute(reinterpret_cast<const void*>(gemm_gup8),
                      hipFuncAttributeMaxDynamicSharedMemorySize, 131072);

  cvt_kernel<<<1024, 256, 0, stream>>>((const float4*)x,  (ushort4*)xb,  8388608 / 4);
  cvt_kernel<<<2048, 256, 0, stream>>>((const float4*)Wg, (ushort4*)wgb, 45088768 / 4);
  cvt_kernel<<<2048, 256, 0, stream>>>((const float4*)Wu, (ushort4*)wub, 45088768 / 4);

  lora_t_kernel<<<32, 256, 0, stream>>>(xb, 4096, Ag, Au, lidx, lay, tg, tu);

  gemm_gup8<<<dim3(8, 86), 512, 131072, stream>>>(xb, wgb, wub, tg, tu, Bg, Bu,
                                                  lidx, lay, gbuf, ubuf);

  swiglu_kernel<<<2048, 256, 0, stream>>>((uint4*)gbuf, (const uint4*)ubuf, 2818048);

  cvt_kernel<<<2048, 256, 0, stream>>>((const float4*)Wd, (ushort4*)wdb2, 45088768 / 4);

  lora_t_kernel<<<32, 256, 0, stream>>>(gbuf, 11008, Ad, nullptr, lidx, lay, td, nullptr);

  gemm_down<<<dim3(16, 32), 256, 0, stream>>>(gbuf, wdb2, td, Bd, lidx, lay, out);
}

// Round 5
// 828.485 us; speedup vs baseline: 3.3425x; 1.3281x over previous
//
#include <hip/hip_runtime.h>
#include <hip/hip_bf16.h>

typedef __bf16 bf16x8 __attribute__((ext_vector_type(8)));
typedef float  f32x4  __attribute__((ext_vector_type(4)));
typedef unsigned short u16;

#define GLDS16(gsrc, ldst)                                                        \
  __builtin_amdgcn_global_load_lds(                                               \
      (const __attribute__((address_space(1))) unsigned int*)(gsrc),              \
      (__attribute__((address_space(3))) unsigned int*)(ldst), 16, 0, 0)

#define BAR() __builtin_amdgcn_s_barrier()
#define WAIT_LGKM0() asm volatile("s_waitcnt lgkmcnt(0)" ::: "memory")
#define WAIT_VM4() asm volatile("s_waitcnt vmcnt(4)" ::: "memory")

__device__ __forceinline__ u16 f2b(float f) {
  unsigned int u = __builtin_bit_cast(unsigned int, f);
  u = (u + 0x7fffu + ((u >> 16) & 1u)) >> 16;
  return (u16)u;
}
__device__ __forceinline__ float b2f(u16 b) {
  unsigned int u = ((unsigned int)b) << 16;
  return __builtin_bit_cast(float, u);
}

// ---------------- fp32 -> bf16 convert ----------------
__global__ __launch_bounds__(256) void cvt_kernel(const float4* __restrict__ in,
                                                  ushort4* __restrict__ out, int n4) {
  int i = blockIdx.x * blockDim.x + threadIdx.x;
  int stride = gridDim.x * blockDim.x;
  for (; i < n4; i += stride) {
    float4 v = in[i];
    ushort4 o;
    o.x = f2b(v.x); o.y = f2b(v.y); o.z = f2b(v.z); o.w = f2b(v.w);
    out[i] = o;
  }
}

// ------ LoRA rank-projection, wave-K-split: t_bf16[m][r] = 0.5*sum_k Xb[m][k]*A[r][k]
// grid 128 x 256thr; block = 16 rows; each of 4 waves does K/4, LDS-reduce.
__global__ __launch_bounds__(256) void lora_t2(const u16* __restrict__ Xb, int K,
                                               const float* __restrict__ A1,
                                               const float* __restrict__ A2,
                                               const int* __restrict__ lidx,
                                               const int* __restrict__ layer,
                                               u16* __restrict__ t1,
                                               u16* __restrict__ t2) {
  __shared__ float red1[4][64][4];
  __shared__ float red2[4][64][4];
  const int lane = threadIdx.x & 63, wid = threadIdx.x >> 6;
  const int m0 = blockIdx.x * 16;
  const int li = lidx[m0 >> 9];
  const size_t abase = ((size_t)layer[0] * 16 + li) * 16 * (size_t)K;
  const int r = lane & 15, kg = lane >> 4;
  const int Kq = K >> 2, kb = wid * Kq;
  f32x4 acc1 = {0.f, 0.f, 0.f, 0.f}, acc2 = {0.f, 0.f, 0.f, 0.f};
  for (int k0 = kb; k0 < kb + Kq; k0 += 32) {
    bf16x8 a = *(const bf16x8*)&Xb[(size_t)(m0 + r) * K + k0 + kg * 8];
    const float* ap = A1 + abase + (size_t)r * K + k0 + kg * 8;
    float4 f0 = *(const float4*)ap;
    float4 f1 = *(const float4*)(ap + 4);
    bf16x8 b;
    b[0] = (__bf16)f0.x; b[1] = (__bf16)f0.y; b[2] = (__bf16)f0.z; b[3] = (__bf16)f0.w;
    b[4] = (__bf16)f1.x; b[5] = (__bf16)f1.y; b[6] = (__bf16)f1.z; b[7] = (__bf16)f1.w;
    acc1 = __builtin_amdgcn_mfma_f32_16x16x32_bf16(a, b, acc1, 0, 0, 0);
    if (A2) {
      const float* ap2 = A2 + abase + (size_t)r * K + k0 + kg * 8;
      float4 g0 = *(const float4*)ap2;
      float4 g1 = *(const float4*)(ap2 + 4);
      bf16x8 b2;
      b2[0] = (__bf16)g0.x; b2[1] = (__bf16)g0.y; b2[2] = (__bf16)g0.z; b2[3] = (__bf16)g0.w;
      b2[4] = (__bf16)g1.x; b2[5] = (__bf16)g1.y; b2[6] = (__bf16)g1.z; b2[7] = (__bf16)g1.w;
      acc2 = __builtin_amdgcn_mfma_f32_16x16x32_bf16(a, b2, acc2, 0, 0, 0);
    }
  }
#pragma unroll
  for (int j = 0; j < 4; ++j) {
    red1[wid][lane][j] = acc1[j];
    if (A2) red2[wid][lane][j] = acc2[j];
  }
  __syncthreads();
  if (wid == 0) {
#pragma unroll
    for (int j = 0; j < 4; ++j) {
      int m = m0 + kg * 4 + j;
      float v1 = red1[0][lane][j] + red1[1][lane][j] + red1[2][lane][j] + red1[3][lane][j];
      t1[(size_t)m * 16 + r] = f2b(0.5f * v1);
      if (A2) {
        float v2 = red2[0][lane][j] + red2[1][lane][j] + red2[2][lane][j] + red2[3][lane][j];
        t2[(size_t)m * 16 + r] = f2b(0.5f * v2);
      }
    }
  }
}

// ===================== shared 8-phase tile macros =====================
#define RD_A(dst, buf, mh) do {                                                \
    _Pragma("unroll")                                                          \
    for (int mf_ = 0; mf_ < 4; ++mf_)                                          \
      _Pragma("unroll")                                                        \
      for (int ks_ = 0; ks_ < 2; ++ks_) {                                      \
        int row_ = wm * 128 + (mh) * 64 + mf_ * 16 + lr;                       \
        int sl_ = (ks_ * 4 + kg) ^ rx;                                         \
        dst[mf_][ks_] = *(const bf16x8*)&sA[(buf) * 16384 + row_ * 64 + sl_ * 8]; \
      }                                                                        \
  } while (0)

#define RD_B(dst, buf, nh) do {                                                \
    _Pragma("unroll")                                                          \
    for (int nf_ = 0; nf_ < 2; ++nf_)                                          \
      _Pragma("unroll")                                                        \
      for (int ks_ = 0; ks_ < 2; ++ks_) {                                      \
        int row_ = wn * 64 + (nh) * 32 + nf_ * 16 + lr;                        \
        int sl_ = (ks_ * 4 + kg) ^ rx;                                         \
        dst[nf_][ks_] = *(const bf16x8*)&sB[(buf) * 16384 + row_ * 64 + sl_ * 8]; \
      }                                                                        \
  } while (0)

#define MMA_Q(AF, BF, mb, nb) do {                                             \
    __builtin_amdgcn_s_setprio(1);                                             \
    _Pragma("unroll")                                                          \
    for (int mf_ = 0; mf_ < 4; ++mf_)                                          \
      _Pragma("unroll")                                                        \
      for (int nf_ = 0; nf_ < 2; ++nf_)                                        \
        _Pragma("unroll")                                                      \
        for (int ks_ = 0; ks_ < 2; ++ks_)                                      \
          acc[(mb) + mf_][(nb) + nf_] = __builtin_amdgcn_mfma_f32_16x16x32_bf16( \
              AF[mf_][ks_], BF[nf_][ks_], acc[(mb) + mf_][(nb) + nf_], 0, 0, 0); \
    __builtin_amdgcn_s_setprio(0);                                             \
  } while (0)

// ================= 8-phase 256x256 fused gate|up GEMM =================
#define STAGE(buf, half, kt) do {                                              \
    int r0_ = ((half) & 1) * 128;                                              \
    const u16* gs_ = ((half) < 2)                                              \
        ? (Xb + (size_t)(m0 + r0_) * 4096 + (size_t)(kt) * 64)                 \
        : (W + (size_t)(n0 + r0_) * 4096 + (size_t)(kt) * 64);                 \
    u16* ld_ = (((half) < 2) ? sA : sB) + (buf) * 16384 + r0_ * 64;            \
    _Pragma("unroll")                                                          \
    for (int i_ = 0; i_ < 2; ++i_) {                                           \
      int ub_ = (wid << 6) + i_ * 512;                                         \
      int un_ = ub_ + lane;                                                    \
      int ur_ = un_ >> 3, us_ = (un_ & 7) ^ (ur_ & 7);                         \
      GLDS16(gs_ + (size_t)ur_ * 4096 + us_ * 8, ld_ + ub_ * 8);               \
    }                                                                          \
  } while (0)

__global__ __launch_bounds__(512, 2) void gemm_gup8(
    const u16* __restrict__ Xb, const u16* __restrict__ Wg, const u16* __restrict__ Wu,
    const u16* __restrict__ tg, const u16* __restrict__ tu,
    const float* __restrict__ Bg, const float* __restrict__ Bu,
    const int* __restrict__ lidx, const int* __restrict__ layer,
    u16* __restrict__ gout, u16* __restrict__ uout) {
  constexpr int F = 11008;
  extern __shared__ u16 smem[];
  u16* sA = smem;            // [2][256*64]
  u16* sB = smem + 32768;    // [2][256*64]
  const int tid = threadIdx.x, lane = tid & 63, wid = tid >> 6;
  const int lr = lane & 15, kg = lane >> 4, rx = lr & 7;
  const int wm = wid >> 2, wn = wid & 3;
  const bool isUp = blockIdx.y >= 43;
  const int m0 = blockIdx.x * 256;
  const int n0 = (isUp ? blockIdx.y - 43 : blockIdx.y) * 256;
  const u16* W = isUp ? Wu : Wg;
  const u16* tb = isUp ? tu : tg;
  const float* Bw = isUp ? Bu : Bg;
  u16* ob = isUp ? uout : gout;

  f32x4 acc[8][4] = {};
  bf16x8 a0[4][2], a1[4][2], b0[2][2], b1[2][2];

  STAGE(0, 0, 0); STAGE(0, 1, 0); STAGE(0, 2, 0); STAGE(0, 3, 0);
  STAGE(1, 2, 1); STAGE(1, 3, 1);
  WAIT_VM4(); BAR();

#pragma unroll 1
  for (int u = 0; u < 32; ++u) {
    const int ktA = (2 * u + 1) & 63;
    const int kt0 = (2 * u + 2) & 63;
    const int kt1 = (2 * u + 3) & 63;
    RD_A(a0, 0, 0); RD_B(b0, 0, 0);
    STAGE(1, 0, ktA);
    BAR(); WAIT_LGKM0();
    MMA_Q(a0, b0, 0, 0);
    BAR();
    RD_B(b1, 0, 1);
    STAGE(1, 1, ktA);
    BAR(); WAIT_LGKM0();
    MMA_Q(a0, b1, 0, 2);
    BAR();
    RD_A(a1, 0, 1);
    STAGE(0, 2, kt0);
    BAR(); WAIT_LGKM0();
    MMA_Q(a1, b1, 4, 2);
    BAR();
    STAGE(0, 3, kt0);
    BAR();
    MMA_Q(a1, b0, 4, 0);
    WAIT_VM4();
    BAR();
    RD_A(a0, 1, 0); RD_B(b0, 1, 0);
    STAGE(0, 0, kt0);
    BAR(); WAIT_LGKM0();
    MMA_Q(a0, b0, 0, 0);
    BAR();
    RD_B(b1, 1, 1);
    STAGE(0, 1, kt0);
    BAR(); WAIT_LGKM0();
    MMA_Q(a0, b1, 0, 2);
    BAR();
    RD_A(a1, 1, 1);
    STAGE(1, 2, kt1);
    BAR(); WAIT_LGKM0();
    MMA_Q(a1, b1, 4, 2);
    BAR();
    STAGE(1, 3, kt1);
    BAR();
    MMA_Q(a1, b0, 4, 0);
    WAIT_VM4();
    BAR();
  }

  // ---- LoRA via MFMA (K=16 padded to 32), then bf16 store ----
  const int li = lidx[m0 >> 9];
  const size_t bbase = ((size_t)layer[0] * 16 + li) * (size_t)F * 16;
  bf16x8 la[8], lb[4];
  const bf16x8 zz = {};
#pragma unroll
  for (int mf = 0; mf < 8; ++mf) {
    int row = m0 + wm * 128 + mf * 16 + lr;
    la[mf] = (kg < 2) ? *(const bf16x8*)&tb[(size_t)row * 16 + kg * 8] : zz;
  }
#pragma unroll
  for (int nf = 0; nf < 4; ++nf) {
    int col = n0 + wn * 64 + nf * 16 + lr;
    if (kg < 2) {
      const float* bp = Bw + bbase + (size_t)col * 16 + kg * 8;
      float4 f0 = *(const float4*)bp;
      float4 f1 = *(const float4*)(bp + 4);
      bf16x8 v;
      v[0] = (__bf16)f0.x; v[1] = (__bf16)f0.y; v[2] = (__bf16)f0.z; v[3] = (__bf16)f0.w;
      v[4] = (__bf16)f1.x; v[5] = (__bf16)f1.y; v[6] = (__bf16)f1.z; v[7] = (__bf16)f1.w;
      lb[nf] = v;
    } else lb[nf] = zz;
  }
#pragma unroll
  for (int mf = 0; mf < 8; ++mf)
#pragma unroll
    for (int nf = 0; nf < 4; ++nf)
      acc[mf][nf] = __builtin_amdgcn_mfma_f32_16x16x32_bf16(la[mf], lb[nf], acc[mf][nf], 0, 0, 0);

#pragma unroll
  for (int mf = 0; mf < 8; ++mf)
#pragma unroll
    for (int nf = 0; nf < 4; ++nf)
#pragma unroll
      for (int j = 0; j < 4; ++j) {
        int row = m0 + wm * 128 + mf * 16 + kg * 4 + j;
        int col = n0 + wn * 64 + nf * 16 + lr;
        ob[(size_t)row * F + col] = f2b(acc[mf][nf][j]);
      }
}

// ================= 8-phase 256x256 down GEMM, K-split=2, fp32 partials =========
#define STAGE_D(buf, half, kt) do {                                           \
    int r0_ = ((half) & 1) * 128;                                             \
    const u16* gs_ = ((half) < 2)                                             \
        ? (Ab + (size_t)(m0 + r0_) * 11008 + (size_t)(kt) * 64)               \
        : (Wd + (size_t)(n0 + r0_) * 11008 + (size_t)(kt) * 64);              \
    u16* ld_ = (((half) < 2) ? sA : sB) + (buf) * 16384 + r0_ * 64;           \
    _Pragma("unroll")                                                         \
    for (int i_ = 0; i_ < 2; ++i_) {                                          \
      int ub_ = (wid << 6) + i_ * 512;                                        \
      int un_ = ub_ + lane;                                                   \
      int ur_ = un_ >> 3, us_ = (un_ & 7) ^ (ur_ & 7);                        \
      GLDS16(gs_ + (size_t)ur_ * 11008 + us_ * 8, ld_ + ub_ * 8);             \
    }                                                                         \
  } while (0)

#define KT(t) (kbase + ((t) >= 86 ? (t) - 86 : (t)))

__global__ __launch_bounds__(512, 2) void gemm_down8(
    const u16* __restrict__ Ab, const u16* __restrict__ Wd,
    float* __restrict__ P0, float* __restrict__ P1) {
  constexpr int H = 4096;
  extern __shared__ u16 smem[];
  u16* sA = smem;
  u16* sB = smem + 32768;
  const int tid = threadIdx.x, lane = tid & 63, wid = tid >> 6;
  const int lr = lane & 15, kg = lane >> 4, rx = lr & 7;
  const int wm = wid >> 2, wn = wid & 3;
  const int m0 = blockIdx.x * 256, n0 = blockIdx.y * 256;
  const int kbase = blockIdx.z * 86;
  float* P = blockIdx.z ? P1 : P0;

  f32x4 acc[8][4] = {};
  bf16x8 a0[4][2], a1[4][2], b0[2][2], b1[2][2];

  STAGE_D(0, 0, KT(0)); STAGE_D(0, 1, KT(0)); STAGE_D(0, 2, KT(0)); STAGE_D(0, 3, KT(0));
  STAGE_D(1, 2, KT(1)); STAGE_D(1, 3, KT(1));
  WAIT_VM4(); BAR();

#pragma unroll 1
  for (int u = 0; u < 43; ++u) {
    const int ktA = KT(2 * u + 1);
    const int kt0 = KT(2 * u + 2);
    const int kt1 = KT(2 * u + 3);
    RD_A(a0, 0, 0); RD_B(b0, 0, 0);
    STAGE_D(1, 0, ktA);
    BAR(); WAIT_LGKM0();
    MMA_Q(a0, b0, 0, 0);
    BAR();
    RD_B(b1, 0, 1);
    STAGE_D(1, 1, ktA);
    BAR(); WAIT_LGKM0();
    MMA_Q(a0, b1, 0, 2);
    BAR();
    RD_A(a1, 0, 1);
    STAGE_D(0, 2, kt0);
    BAR(); WAIT_LGKM0();
    MMA_Q(a1, b1, 4, 2);
    BAR();
    STAGE_D(0, 3, kt0);
    BAR();
    MMA_Q(a1, b0, 4, 0);
    WAIT_VM4();
    BAR();
    RD_A(a0, 1, 0); RD_B(b0, 1, 0);
    STAGE_D(0, 0, kt0);
    BAR(); WAIT_LGKM0();
    MMA_Q(a0, b0, 0, 0);
    BAR();
    RD_B(b1, 1, 1);
    STAGE_D(0, 1, kt0);
    BAR(); WAIT_LGKM0();
    MMA_Q(a0, b1, 0, 2);
    BAR();
    RD_A(a1, 1, 1);
    STAGE_D(1, 2, kt1);
    BAR(); WAIT_LGKM0();
    MMA_Q(a1, b1, 4, 2);
    BAR();
    STAGE_D(1, 3, kt1);
    BAR();
    MMA_Q(a1, b0, 4, 0);
    WAIT_VM4();
    BAR();
  }

#pragma unroll
  for (int mf = 0; mf < 8; ++mf)
#pragma unroll
    for (int nf = 0; nf < 4; ++nf)
#pragma unroll
      for (int j = 0; j < 4; ++j) {
        int row = m0 + wm * 128 + mf * 16 + kg * 4 + j;
        int col = n0 + wn * 64 + nf * 16 + lr;
        P[(size_t)row * H + col] = acc[mf][nf][j];
      }
}

// ---------------- combine: out = P0 + P1 + td.Bd^T (LoRA down) ----------------
__global__ __launch_bounds__(256) void combine_down(
    const float4* __restrict__ P0, const float4* __restrict__ P1,
    const u16* __restrict__ td, const float* __restrict__ Bd,
    const int* __restrict__ lidx, const int* __restrict__ layer,
    float4* __restrict__ out) {
  constexpr int H = 4096;
  int gid = blockIdx.x * 256 + threadIdx.x;  // 2048 * 1024 threads
  int m = gid >> 10, h4 = gid & 1023;
  int li = lidx[m >> 9];
  const float* bb = Bd + ((size_t)(layer[0] * 16 + li) * H + h4 * 4) * 16;
  float tv[16];
  uint4 ta = *(const uint4*)&td[(size_t)m * 16];
  uint4 tb_ = *(const uint4*)&td[(size_t)m * 16 + 8];
  const unsigned* tw = (const unsigned*)&ta;
  const unsigned* tw2 = (const unsigned*)&tb_;
#pragma unroll
  for (int q = 0; q < 4; ++q) {
    tv[q * 2]     = __builtin_bit_cast(float, tw[q] << 16);
    tv[q * 2 + 1] = __builtin_bit_cast(float, tw[q] & 0xffff0000u);
    tv[8 + q * 2]     = __builtin_bit_cast(float, tw2[q] << 16);
    tv[8 + q * 2 + 1] = __builtin_bit_cast(float, tw2[q] & 0xffff0000u);
  }
  float4 p0 = P0[gid], p1 = P1[gid];
  float o[4];
#pragma unroll
  for (int q = 0; q < 4; ++q) {
    float s = 0.f;
#pragma unroll
    for (int r = 0; r < 16; ++r) s += tv[r] * bb[q * 16 + r];
    o[q] = s;
  }
  out[gid] = make_float4(p0.x + p1.x + o[0], p0.y + p1.y + o[1],
                         p0.z + p1.z + o[2], p0.w + p1.w + o[3]);
}

// ---------------- swiglu: g = silu(g) * u (bf16, 8 elems/thread) ----------------
__global__ __launch_bounds__(256) void swiglu_kernel(uint4* __restrict__ g,
                                                     const uint4* __restrict__ u, int n) {
  int i = blockIdx.x * 256 + threadIdx.x, st = gridDim.x * 256;
  for (; i < n; i += st) {
    uint4 gv = g[i], uv = u[i], ov;
    unsigned* gw = (unsigned*)&gv;
    unsigned* uw = (unsigned*)&uv;
    unsigned* ow = (unsigned*)&ov;
#pragma unroll
    for (int q = 0; q < 4; ++q) {
      float g0 = __builtin_bit_cast(float, gw[q] << 16);
      float g1 = __builtin_bit_cast(float, gw[q] & 0xffff0000u);
      float u0 = __builtin_bit_cast(float, uw[q] << 16);
      float u1 = __builtin_bit_cast(float, uw[q] & 0xffff0000u);
      float a0 = g0 / (1.f + __expf(-g0)) * u0;
      float a1 = g1 / (1.f + __expf(-g1)) * u1;
      ow[q] = (unsigned)f2b(a0) | ((unsigned)f2b(a1) << 16);
    }
    g[i] = ov;
  }
}

extern "C" void kernel_launch(void* const* d_in, const int* in_sizes, int n_in,
                              void* d_out, int out_size, void* d_ws, size_t ws_size,
                              hipStream_t stream) {
  const float* x  = (const float*)d_in[0];
  const float* Wg = (const float*)d_in[1];
  const float* Wu = (const float*)d_in[2];
  const float* Wd = (const float*)d_in[3];
  const float* Ag = (const float*)d_in[4];
  const float* Bg = (const float*)d_in[5];
  const float* Au = (const float*)d_in[6];
  const float* Bu = (const float*)d_in[7];
  const float* Ad = (const float*)d_in[8];
  const float* Bd = (const float*)d_in[9];
  const int* lidx = (const int*)d_in[10];
  const int* lay  = (const int*)d_in[11];
  float* out = (float*)d_out;

  // ws layout (bytes); regions reused across phases:
  //   wgb slot -> Wd bf16 after gup8; wub slot -> P1; ubuf slot -> P0.
  char* ws = (char*)d_ws;
  u16*  xb   = (u16*)(ws + 0);            //  16,777,216  x bf16 [2048][4096]
  u16*  wgb  = (u16*)(ws + 16777216);     //  90,177,536  Wg bf16 [11008][4096]
  u16*  wub  = (u16*)(ws + 106954752);    //  90,177,536  Wu bf16
  u16*  gbuf = (u16*)(ws + 197132288);    //  45,088,768  gate -> act bf16 [2048][11008]
  u16*  ubuf = (u16*)(ws + 242221056);    //  45,088,768  up bf16
  u16*  tg   = (u16*)(ws + 287309824);    //  65,536
  u16*  tu   = (u16*)(ws + 287375360);    //  65,536
  u16*  td   = (u16*)(ws + 287440896);    //  65,536
  u16*  wdb2 = wgb;                       //  Wd bf16 [4096][11008] (after gup8)
  float* P0  = (float*)ubuf;              //  33,554,432 fp32 [2048][4096] (after swiglu)
  float* P1  = (float*)wub;               //  33,554,432 fp32 (after gup8)

  hipFuncSetAttribute(reinterpret_cast<const void*>(gemm_gup8),
                      hipFuncAttributeMaxDynamicSharedMemorySize, 131072);
  hipFuncSetAttribute(reinterpret_cast<const void*>(gemm_down8),
                      hipFuncAttributeMaxDynamicSharedMemorySize, 131072);

  cvt_kernel<<<1024, 256, 0, stream>>>((const float4*)x,  (ushort4*)xb,  8388608 / 4);
  cvt_kernel<<<2048, 256, 0, stream>>>((const float4*)Wg, (ushort4*)wgb, 45088768 / 4);
  cvt_kernel<<<2048, 256, 0, stream>>>((const float4*)Wu, (ushort4*)wub, 45088768 / 4);

  lora_t2<<<128, 256, 0, stream>>>(xb, 4096, Ag, Au, lidx, lay, tg, tu);

  gemm_gup8<<<dim3(8, 86), 512, 131072, stream>>>(xb, wgb, wub, tg, tu, Bg, Bu,
                                                  lidx, lay, gbuf, ubuf);

  swiglu_kernel<<<2048, 256, 0, stream>>>((uint4*)gbuf, (const uint4*)ubuf, 2818048);

  cvt_kernel<<<2048, 256, 0, stream>>>((const float4*)Wd, (ushort4*)wdb2, 45088768 / 4);

  lora_t2<<<128, 256, 0, stream>>>(gbuf, 11008, Ad, nullptr, lidx, lay, td, nullptr);

  gemm_down8<<<dim3(8, 16, 2), 512, 131072, stream>>>(gbuf, wdb2, P0, P1);

  combine_down<<<8192, 256, 0, stream>>>((const float4*)P0, (const float4*)P1,
                                         td, Bd, lidx, lay, (float4*)out);
}